// Round 3
// baseline (266.110 us; speedup 1.0000x reference)
//
#include <hip/hip_runtime.h>

// ---------------------------------------------------------------------------
// RefineIUGraphLayer: D=256, H=16, HD=16, N=16384, B=64, S=128, M=8192
//   1) qkv  = seq_feat @ in_proj_w^T + b       (bf16 MFMA gemm, bf16 out)
//   2) attn = MHA(qkv)                         (f32 per-thread, bf16 in/out)
//   3) seq  = attn @ out_proj_w^T + b          (bf16 MFMA gemm, bf16 out)
//   4) agg  = p1norm(user @ seq^T) @ seq / M   (fused, dbuf LDS, j-split x2)
//   5) out  = user + agg @ trans_w^T + b       (bf16 MFMA gemm, f32 out)
// ---------------------------------------------------------------------------

typedef __bf16 bf16_t;
typedef __bf16 bf16x8 __attribute__((ext_vector_type(8)));
typedef __bf16 bf16x4 __attribute__((ext_vector_type(4)));
typedef float  f32x4  __attribute__((ext_vector_type(4)));
typedef unsigned int u32x4 __attribute__((ext_vector_type(4)));

#define MFMA16(a, b, c) __builtin_amdgcn_mfma_f32_16x16x32_bf16((a), (b), (c), 0, 0, 0)

// 3-bit chunk XOR swizzles (write & read identically; involution).
__device__ __forceinline__ int swz256(int row, int k) { return row * 256 + (k ^ ((row & 7) << 3)); }
__device__ __forceinline__ int swz64 (int row, int k) { return row * 64  + (k ^ ((row & 7) << 3)); }
// P-tile byte swizzle: balanced for b16 writes AND b128 reads.
__device__ __forceinline__ int pswz(int row) { return ((row & 3) << 4) ^ (((row >> 2) & 3) << 5); }

// --------------------------- f32 -> bf16 convert ---------------------------
__global__ void k_cvt(const float* __restrict__ s, bf16_t* __restrict__ d, int n4) {
    int i  = blockIdx.x * blockDim.x + threadIdx.x;
    int st = gridDim.x * blockDim.x;
    for (; i < n4; i += st) {
        float4 v = ((const float4*)s)[i];
        bf16x4 o = { (bf16_t)v.x, (bf16_t)v.y, (bf16_t)v.z, (bf16_t)v.w };
        ((bf16x4*)d)[i] = o;
    }
}

// ----------------- bf16 transpose [8192,256] -> [256,8192] -----------------
__global__ void k_transpose(const bf16_t* __restrict__ s, bf16_t* __restrict__ d) {
    __shared__ bf16_t t[64][65];
    const int c0 = blockIdx.x * 64;   // d base
    const int r0 = blockIdx.y * 64;   // j base
    const int tid = threadIdx.x;
#pragma unroll
    for (int i = 0; i < 16; ++i) {
        int e = i * 256 + tid;
        int lr = e >> 6, lc = e & 63;
        t[lc][lr] = s[(size_t)(r0 + lr) * 256 + c0 + lc];
    }
    __syncthreads();
#pragma unroll
    for (int i = 0; i < 16; ++i) {
        int e = i * 256 + tid;
        int lr = e >> 6, lc = e & 63;
        d[(size_t)(c0 + lr) * 8192 + r0 + lc] = t[lr][lc];
    }
}

// --------------- generic C = A @ B^T + bias (+resid), f32/bf16 out ---------
__global__ __launch_bounds__(256, 1)
void k_gemm_bt(const bf16_t* __restrict__ A, const bf16_t* __restrict__ B,
               const float* __restrict__ bias, const float* __restrict__ resid,
               float* __restrict__ C, bf16_t* __restrict__ Cb, int N) {
    __shared__ bf16_t Al[64 * 256];
    __shared__ bf16_t Bl[64 * 256];
    const int tid  = threadIdx.x;
    const int lane = tid & 63;
    const int w    = tid >> 6;
    const int l15  = lane & 15;
    const int l4   = lane >> 4;
    const int rb = blockIdx.y * 64, cb = blockIdx.x * 64;

    {
        const u32x4* sa = (const u32x4*)(A + (size_t)rb * 256);
        const u32x4* sb = (const u32x4*)(B + (size_t)cb * 256);
        u32x4* da = (u32x4*)Al;
        u32x4* db = (u32x4*)Bl;
#pragma unroll
        for (int i = 0; i < 8; ++i) {
            int ch  = i * 256 + tid;
            int row = ch >> 5, cp = ch & 31;
            int sch = (ch & ~31) | (cp ^ (row & 7));
            da[sch] = sa[ch];
            db[sch] = sb[ch];
        }
    }
    __syncthreads();

    f32x4 acc[4];
#pragma unroll
    for (int n = 0; n < 4; ++n) acc[n] = (f32x4){0.f, 0.f, 0.f, 0.f};

#pragma unroll
    for (int t = 0; t < 8; ++t) {
        int k = t * 32 + l4 * 8;
        bf16x8 af = *(const bf16x8*)(Al + swz256(16 * w + l15, k));
#pragma unroll
        for (int n = 0; n < 4; ++n) {
            bf16x8 bfr = *(const bf16x8*)(Bl + swz256(16 * n + l15, k));
            acc[n] = MFMA16(af, bfr, acc[n]);
        }
    }

#pragma unroll
    for (int n = 0; n < 4; ++n) {
        int col = cb + 16 * n + l15;
        float bv = bias ? bias[col] : 0.f;
#pragma unroll
        for (int r = 0; r < 4; ++r) {
            int row = rb + 16 * w + l4 * 4 + r;
            size_t idx = (size_t)row * N + col;
            float v = acc[n][r] + bv;
            if (resid) v += resid[idx];
            if (Cb) Cb[idx] = (bf16_t)v; else C[idx] = v;
        }
    }
}

// ------------------------------- MHA (bf16 I/O) ----------------------------
__global__ __launch_bounds__(128, 1)
void k_mha(const bf16_t* __restrict__ qkv, bf16_t* __restrict__ attn) {
    __shared__ float Kl[128][17];
    __shared__ float Vl[128][17];
    const int bh = blockIdx.x;
    const int b = bh >> 4, h = bh & 15;
    const int t = threadIdx.x;
    const size_t rowbase = (size_t)b * 128;

    const bf16_t* base = qkv + (rowbase + t) * 768 + h * 16;
    bf16x8 qa = *(const bf16x8*)(base),       qb = *(const bf16x8*)(base + 8);
    bf16x8 ka = *(const bf16x8*)(base + 256), kb = *(const bf16x8*)(base + 264);
    bf16x8 va = *(const bf16x8*)(base + 512), vb = *(const bf16x8*)(base + 520);
    float q[16];
#pragma unroll
    for (int e = 0; e < 8; ++e) {
        q[e] = (float)qa[e]; q[8 + e] = (float)qb[e];
        Kl[t][e] = (float)ka[e]; Kl[t][8 + e] = (float)kb[e];
        Vl[t][e] = (float)va[e]; Vl[t][8 + e] = (float)vb[e];
    }
    __syncthreads();

    float m = -1e30f;
    for (int j = 0; j < 128; ++j) {
        float s = 0.f;
#pragma unroll
        for (int d = 0; d < 16; ++d) s += q[d] * Kl[j][d];
        m = fmaxf(m, s * 0.25f);
    }
    float sum = 0.f;
    float o[16];
#pragma unroll
    for (int d = 0; d < 16; ++d) o[d] = 0.f;
    for (int j = 0; j < 128; ++j) {
        float s = 0.f;
#pragma unroll
        for (int d = 0; d < 16; ++d) s += q[d] * Kl[j][d];
        float e = __expf(s * 0.25f - m);
        sum += e;
#pragma unroll
        for (int d = 0; d < 16; ++d) o[d] += e * Vl[j][d];
    }
    float inv = 1.f / sum;
    bf16_t* out = attn + (rowbase + t) * 256 + h * 16;
#pragma unroll
    for (int d = 0; d < 16; ++d) out[d] = (bf16_t)(o[d] * inv);
}

// ------------------- fused user-attention (the hot loop) -------------------
// BQ=128 q-rows per block, one j-half (4096 j, 64 iters of 64). 8 waves
// (4 wr x 2 wc). U register-resident; Kl/Tl double-buffered so staging
// writes overlap PV; 2 barriers/iter. Rowsum partials -> rsp2 (no atomics).
__global__ __launch_bounds__(512, 2)
void k_user_attn(const bf16_t* __restrict__ Ub, const bf16_t* __restrict__ Sq,
                 const bf16_t* __restrict__ SqT, bf16_t* __restrict__ Opart,
                 float* __restrict__ rsp2) {
    __shared__ bf16_t Kl[2][64 * 256];   // seq tile  [64 j][256 d]  2x32 KB
    __shared__ bf16_t Tl[2][256 * 64];   // seqT tile [256 d][64 j]  2x32 KB
    __shared__ bf16_t Pl[128 * 64];      // scores    [128 q][64 j]  16 KB

    const int tid  = threadIdx.x;
    const int lane = tid & 63;
    const int wid  = tid >> 6;     // 0..7
    const int wr   = wid >> 1;     // 0..3 : 32-row q strip
    const int wc   = wid & 1;      // 0..1 : j/d column half
    const int l15  = lane & 15;
    const int l4   = lane >> 4;
    const int q0   = blockIdx.x * 128;
    const int jy   = blockIdx.y;   // 0..1
    const int jbase = jy * 4096;

    // U fragments in registers: rows q0 + 32*wr + 16*rt + l15, k = t*32 + l4*8
    bf16x8 uf[2][8];
#pragma unroll
    for (int rt = 0; rt < 2; ++rt) {
        const bf16_t* up = Ub + (size_t)(q0 + 32 * wr + 16 * rt + l15) * 256 + l4 * 8;
#pragma unroll
        for (int t = 0; t < 8; ++t) uf[rt][t] = *(const bf16x8*)(up + t * 32);
    }

    f32x4 oacc[2][8];
#pragma unroll
    for (int rt = 0; rt < 2; ++rt)
#pragma unroll
        for (int n = 0; n < 8; ++n) oacc[rt][n] = (f32x4){0.f, 0.f, 0.f, 0.f};
    float rsacc[2][4] = {{0.f, 0.f, 0.f, 0.f}, {0.f, 0.f, 0.f, 0.f}};

    u32x4 sreg[4], treg[4];
    auto load_tiles = [&](int j0) {
        const u32x4* src = (const u32x4*)(Sq + (size_t)j0 * 256);
#pragma unroll
        for (int i = 0; i < 4; ++i) sreg[i] = src[i * 512 + tid];
#pragma unroll
        for (int i = 0; i < 4; ++i) {
            int ch = i * 512 + tid;           // 0..2047
            int dr = ch >> 3, cp = ch & 7;    // d row, 16B chunk
            treg[i] = *(const u32x4*)(SqT + (size_t)dr * 8192 + j0 + cp * 8);
        }
    };
    auto write_tiles = [&](int b) {
        u32x4* dk = (u32x4*)(&Kl[b][0]);
        u32x4* dt = (u32x4*)(&Tl[b][0]);
#pragma unroll
        for (int i = 0; i < 4; ++i) {
            int ch = i * 512 + tid;
            int row = ch >> 5, cp = ch & 31;
            dk[(ch & ~31) | (cp ^ (row & 7))] = sreg[i];
        }
#pragma unroll
        for (int i = 0; i < 4; ++i) {
            int ch = i * 512 + tid;
            int row = ch >> 3, cp = ch & 7;
            dt[(ch & ~7) | (cp ^ (row & 7))] = treg[i];
        }
    };

    // prologue: tile 0 -> buf0; prefetch tile 1 into regs
    load_tiles(jbase);
    write_tiles(0);
    load_tiles(jbase + 64);

    char* Pb = (char*)Pl;
    for (int it = 0; it < 64; ++it) {
        const int cur = it & 1;
        const bf16_t* Klc = &Kl[cur][0];
        const bf16_t* Tlc = &Tl[cur][0];
        __syncthreads();   // buf[cur] visible; prev PV reads of Pl done

        // ---- S-GEMM: S[128x32(wc)] = U(regs) @ K_tile^T, K=256 ----
        f32x4 sacc[2][2];
#pragma unroll
        for (int rt = 0; rt < 2; ++rt)
#pragma unroll
            for (int jt = 0; jt < 2; ++jt) sacc[rt][jt] = (f32x4){0.f, 0.f, 0.f, 0.f};
#pragma unroll
        for (int t = 0; t < 8; ++t) {
            int k = t * 32 + l4 * 8;
#pragma unroll
            for (int jt = 0; jt < 2; ++jt) {
                bf16x8 bfr = *(const bf16x8*)(Klc + swz256(32 * wc + 16 * jt + l15, k));
#pragma unroll
                for (int rt = 0; rt < 2; ++rt)
                    sacc[rt][jt] = MFMA16(uf[rt][t], bfr, sacc[rt][jt]);
            }
        }
        // ---- |.| row partial sums + P -> bf16 LDS ----
#pragma unroll
        for (int rt = 0; rt < 2; ++rt)
#pragma unroll
            for (int jt = 0; jt < 2; ++jt)
#pragma unroll
                for (int r = 0; r < 4; ++r) {
                    float v = sacc[rt][jt][r];
                    rsacc[rt][r] += fabsf(v);
                    int prow = 32 * wr + 16 * rt + l4 * 4 + r;
                    int pcol = 32 * wc + 16 * jt + l15;
                    *(bf16_t*)(Pb + prow * 128 + ((pcol * 2) ^ pswz(prow))) = (bf16_t)v;
                }
        __syncthreads();   // P visible

        // ---- PV: O[128x128(wc)] += P @ T_tile^T, K=64 ----
#pragma unroll
        for (int kt = 0; kt < 2; ++kt) {
            bf16x8 paf[2];
#pragma unroll
            for (int rt = 0; rt < 2; ++rt) {
                int prow = 32 * wr + 16 * rt + l15;
                paf[rt] = *(const bf16x8*)(Pb + prow * 128 + ((kt * 64 + l4 * 16) ^ pswz(prow)));
            }
#pragma unroll
            for (int n = 0; n < 8; ++n) {
                bf16x8 bfr = *(const bf16x8*)(Tlc + swz64(128 * wc + 16 * n + l15, kt * 32 + l4 * 8));
#pragma unroll
                for (int rt = 0; rt < 2; ++rt)
                    oacc[rt][n] = MFMA16(paf[rt], bfr, oacc[rt][n]);
            }
        }

        // ---- staging of tile it+1 overlaps PV; prefetch tile it+2 ----
        if (it + 1 < 64) write_tiles(cur ^ 1);
        if (it + 2 < 64) load_tiles(jbase + (it + 2) * 64);
    }

    // ---- rowsum partials: 16-lane butterfly, write per-(jy,wc) slot ----
    float* rdst = rsp2 + (size_t)(jy * 2 + wc) * 16384 + q0;
#pragma unroll
    for (int rt = 0; rt < 2; ++rt)
#pragma unroll
        for (int r = 0; r < 4; ++r) {
            float v = rsacc[rt][r];
            v += __shfl_xor(v, 1, 16);
            v += __shfl_xor(v, 2, 16);
            v += __shfl_xor(v, 4, 16);
            v += __shfl_xor(v, 8, 16);
            if (l15 == 0) rdst[32 * wr + 16 * rt + 4 * l4 + r] = v;
        }

    bf16_t* ob = Opart + (size_t)jy * 16384 * 256;
#pragma unroll
    for (int rt = 0; rt < 2; ++rt)
#pragma unroll
        for (int r = 0; r < 4; ++r) {
            int row = q0 + 32 * wr + 16 * rt + l4 * 4 + r;
#pragma unroll
            for (int n = 0; n < 8; ++n)
                ob[(size_t)row * 256 + 128 * wc + 16 * n + l15] = (bf16_t)oacc[rt][n][r];
        }
}

// ---- combine j-halves: agg = (O0+O1) / (max(sum rsp2,1e-12)*8192) ---------
__global__ void k_combine(const bf16_t* __restrict__ O, const float* __restrict__ rsp2,
                          bf16_t* __restrict__ aggb) {
    int idx = blockIdx.x * blockDim.x + threadIdx.x;   // 16384*32 groups of 8
    int row = idx >> 5, g = idx & 31;
    float s = rsp2[row] + rsp2[16384 + row] + rsp2[2 * 16384 + row] + rsp2[3 * 16384 + row];
    float inv = 1.f / (fmaxf(s, 1e-12f) * 8192.f);
    bf16x8 a = *(const bf16x8*)(O + (size_t)row * 256 + g * 8);
    bf16x8 b = *(const bf16x8*)(O + (size_t)16384 * 256 + (size_t)row * 256 + g * 8);
    bf16x8 o;
#pragma unroll
    for (int e = 0; e < 8; ++e) o[e] = (bf16_t)(((float)a[e] + (float)b[e]) * inv);
    *(bf16x8*)(aggb + (size_t)row * 256 + g * 8) = o;
}

// ---------------------------------------------------------------------------
extern "C" void kernel_launch(void* const* d_in, const int* in_sizes, int n_in,
                              void* d_out, int out_size, void* d_ws, size_t ws_size,
                              hipStream_t stream) {
    const float* user_feat  = (const float*)d_in[0];   // [16384,256]
    const float* seq_feat   = (const float*)d_in[1];   // [64,128,256]
    const float* in_proj_w  = (const float*)d_in[2];   // [768,256]
    const float* in_proj_b  = (const float*)d_in[3];   // [768]
    const float* out_proj_w = (const float*)d_in[4];   // [256,256]
    const float* out_proj_b = (const float*)d_in[5];   // [256]
    const float* trans_w    = (const float*)d_in[6];   // [256,256]
    const float* trans_b    = (const float*)d_in[7];   // [256]
    float* out = (float*)d_out;                        // [16384,256]

    char* w = (char*)d_ws;
    size_t off = 0;
    auto take = [&](size_t bytes) { void* p = w + off; off += (bytes + 255) & ~(size_t)255; return p; };
    bf16_t* Ub    = (bf16_t*)take((size_t)16384 * 256 * 2);
    bf16_t* Xb    = (bf16_t*)take((size_t)8192 * 256 * 2);   // dead after gemm2 -> rsp2 here
    bf16_t* W1b   = (bf16_t*)take((size_t)768 * 256 * 2);
    bf16_t* W2b   = (bf16_t*)take((size_t)256 * 256 * 2);
    bf16_t* W3b   = (bf16_t*)take((size_t)256 * 256 * 2);
    bf16_t* attnb = (bf16_t*)take((size_t)8192 * 256 * 2);
    bf16_t* seqb  = (bf16_t*)take((size_t)8192 * 256 * 2);
    bf16_t* seqTb = (bf16_t*)take((size_t)256 * 8192 * 2);
    char*   regA  = (char*)take((size_t)8192 * 768 * 4);     // 25.17 MB shared region
    bf16_t* qkvb  = (bf16_t*)regA;                           // [8192,768] bf16, dies after MHA
    bf16_t* Opart = (bf16_t*)regA;                           // [2,16384,256] bf16 = 16.78 MB
    bf16_t* aggb  = (bf16_t*)(regA + (size_t)2 * 16384 * 256 * 2); // 8.39 MB
    float*  rsp2  = (float*)Xb;                              // [4,16384] f32 (Xb dead by then)

    // 1) bf16 casts of MFMA operands
    k_cvt<<<2048, 256, 0, stream>>>(user_feat, Ub, 16384 * 256 / 4);
    k_cvt<<<2048, 256, 0, stream>>>(seq_feat, Xb, 8192 * 256 / 4);
    k_cvt<<<192, 256, 0, stream>>>(in_proj_w, W1b, 768 * 256 / 4);
    k_cvt<<<64, 256, 0, stream>>>(out_proj_w, W2b, 256 * 256 / 4);
    k_cvt<<<64, 256, 0, stream>>>(trans_w, W3b, 256 * 256 / 4);

    // 2) qkv = seq_feat @ in_proj_w^T + in_proj_b   [8192,768] bf16
    k_gemm_bt<<<dim3(12, 128), 256, 0, stream>>>(Xb, W1b, in_proj_b, nullptr, nullptr, qkvb, 768);

    // 3) MHA -> attn bf16 [8192,256]
    k_mha<<<1024, 128, 0, stream>>>(qkvb, attnb);

    // 4) seq = attn @ out_proj_w^T + out_proj_b   [8192,256] bf16
    k_gemm_bt<<<dim3(4, 128), 256, 0, stream>>>(attnb, W2b, out_proj_b, nullptr, nullptr, seqb, 256);

    // 5) seq^T bf16 [256,8192]
    k_transpose<<<dim3(4, 128), 256, 0, stream>>>(seqb, seqTb);

    // 6) fused user-attention, j-split x2 -> partials
    k_user_attn<<<dim3(128, 2), 512, 0, stream>>>(Ub, seqb, seqTb, Opart, rsp2);

    // 6b) combine partials -> agg bf16 [16384,256]
    k_combine<<<2048, 256, 0, stream>>>(Opart, rsp2, aggb);

    // 7) out = user_feat + agg @ trans_w^T + trans_b
    k_gemm_bt<<<dim3(4, 256), 256, 0, stream>>>(aggb, W3b, trans_b, user_feat, out, nullptr, 256);
}